// Round 1
// 187.720 us; speedup vs baseline: 1.1621x; 1.1621x over previous
//
#include <hip/hip_runtime.h>

#define NUM_E   16384
#define DIM     256
#define NROWS   8192      // B*H*W
#define HW      1024      // H*W
#define BM      128
#define BN      256
#define BK      32
#define NCB     (NUM_E / BN)   // 64 col blocks
// thresholds: bf16 pairwise noise ~2.8e-4 (7 sigma = 2e-3) + 2x key-quantization 1.22e-4
#define GATE    2.5e-3f   // flag threshold
#define TAUC    2.5e-3f   // candidate-qualify threshold
#define EHID    2.5e-3    // hidden-code margin
#define MAXC    16

// 16-B chunk swizzle for staging (chunks 0..3 within a 32-short row)
#define SWZ(r) ((((r) >> 1) ^ ((r) >> 3)) & 3)

typedef __bf16 bf16x8 __attribute__((ext_vector_type(8)));
typedef float  f32x4  __attribute__((ext_vector_type(4)));
typedef float  f32x16 __attribute__((ext_vector_type(16)));

__device__ __forceinline__ unsigned short f2bf(float x) {
    unsigned u = __float_as_uint(x);
    unsigned r = (u + 0x7fffu + ((u >> 16) & 1u)) >> 16;
    return (unsigned short)r;
}
__device__ __forceinline__ void async_copy16(const void* g, void* l) {
    __builtin_amdgcn_global_load_lds(
        (const __attribute__((address_space(1))) unsigned int*)g,
        (__attribute__((address_space(3))) unsigned int*)l, 16, 0, 0);
}
__device__ __forceinline__ int imax(int a, int b) { return a > b ? a : b; }
__device__ __forceinline__ int imin(int a, int b) { return a < b ? a : b; }

// ---------------- z row sum-of-squares partials (grid 32 x 16) ----------------
__global__ void k_sumz(const float* __restrict__ z, float* __restrict__ zpart) {
    int n = blockIdx.x * 256 + threadIdx.x;
    int b = n >> 10, hw = n & 1023;
    int cb = blockIdx.y;
    const float* p = z + (size_t)(b * DIM + cb * 16) * HW + hw;
    float s = 0.f;
    #pragma unroll
    for (int c = 0; c < 16; c++) { float v = p[c * HW]; s += v * v; }
    zpart[cb * NROWS + n] = s;
}

// ---------------- prep z: finalize inv_z in-block + bf16 split (hi only) ---------
__global__ void k_prep_z(const float* __restrict__ z, const float* __restrict__ zpart,
                         unsigned short* __restrict__ Zh) {
    __shared__ float T[64 * 68];
    __shared__ __align__(16) float Tinv[64];
    int t = threadIdx.x;
    int n0 = blockIdx.x * 64, c0 = blockIdx.y * 64;
    int b = n0 >> 10, hw0 = n0 & 1023;
    if (t < 64) {
        float s = 0.f;
        #pragma unroll
        for (int cb = 0; cb < 16; cb++) s += zpart[cb * NROWS + n0 + t];
        Tinv[t] = 1.0f / fmaxf(sqrtf(s), 1e-12f);
    }
    __syncthreads();
    #pragma unroll
    for (int i = 0; i < 4; i++) {
        int f = t + 256 * i;
        int cc = f >> 4, n4 = (f & 15) * 4;
        float4 v  = *(const float4*)(z + (size_t)(b * DIM + c0 + cc) * HW + hw0 + n4);
        float4 iv = *(const float4*)&Tinv[n4];
        v.x *= iv.x; v.y *= iv.y; v.z *= iv.z; v.w *= iv.w;
        *(float4*)&T[cc * 68 + n4] = v;
    }
    __syncthreads();
    #pragma unroll
    for (int i = 0; i < 4; i++) {
        int f = t + 256 * i;
        int nn = f >> 4, c4 = (f & 15) * 4;
        ushort4 h;
        h.x = f2bf(T[(c4+0)*68 + nn]);
        h.y = f2bf(T[(c4+1)*68 + nn]);
        h.z = f2bf(T[(c4+2)*68 + nn]);
        h.w = f2bf(T[(c4+3)*68 + nn]);
        *(ushort4*)(Zh + (size_t)(n0 + nn) * DIM + c0 + c4) = h;
    }
}

// ---------------- prep e: fp64 norm + bf16 hi ----------------
__global__ void k_prep_e(const float* __restrict__ emb, float* __restrict__ inv_e,
                         double* __restrict__ se2, unsigned short* __restrict__ Eh,
                         int* __restrict__ cnt, int* __restrict__ cnt2) {
    if (blockIdx.x == 0 && threadIdx.x == 0) { *cnt = 0; *cnt2 = 0; }
    int wv = threadIdx.x >> 6, lane = threadIdx.x & 63;
    int k = blockIdx.x * 4 + wv;
    float4 v = *(const float4*)(emb + (size_t)k * DIM + lane * 4);
    double sq = (double)v.x*v.x + (double)v.y*v.y + (double)v.z*v.z + (double)v.w*v.w;
    for (int off = 32; off > 0; off >>= 1) sq += __shfl_down(sq, off);
    double tot = fmax(__shfl(sq, 0), 1e-24);
    if (lane == 0) { se2[k] = tot; inv_e[k] = 1.0f / fmaxf((float)sqrt(tot), 1e-12f); }
    float s = 1.0f / fmaxf((float)sqrt(tot), 1e-12f);
    ushort4 h;
    h.x = f2bf(v.x * s); h.y = f2bf(v.y * s); h.z = f2bf(v.z * s); h.w = f2bf(v.w * s);
    *(ushort4*)(Eh + (size_t)k * DIM + lane * 4) = h;
}

// ---------------- MFMA bf16 1-pass score: zh·eh, packed-key top-2 epilogue ----
// keys: v in [-1,1] -> bits(v+2.0f) is positive & order-preserving; low 8 bits
// replaced by block-local column (unique per col -> no exact ties; quantization
// step <= 2^-13, covered by GATE/TAUC/EHID margins + fp64 rescore path).
__launch_bounds__(256, 2)
__global__ void k_score(const unsigned short* __restrict__ Zh,
                        const unsigned short* __restrict__ Eh, f32x4* __restrict__ part) {
    // union: staging 2 x (A 4096 | B 8192) shorts (48 KB)  /  epilogue kv[64][66] int2 (33 KB)
    __shared__ __align__(16) int smem[12288];
    unsigned short* lds = (unsigned short*)smem;
    int* kv = smem;
    const int t = threadIdx.x, l = t & 63, w = t >> 6;
    const int wm = w >> 1, wn = w & 1;      // wave tile 64 x 128
    const int m0 = blockIdx.x * BM;
    const int nb = blockIdx.y * BN;
    const int l31 = l & 31, lh = l >> 5;
    const int sr = l >> 2, sp = l & 3;

    const unsigned short* gA0 = Zh + (size_t)m0 * DIM;
    const unsigned short* gB0 = Eh + (size_t)nb * DIM;

    f32x16 acc[2][4];
    #pragma unroll
    for (int i = 0; i < 2; i++)
        #pragma unroll
        for (int j = 0; j < 4; j++) acc[i][j] = (f32x16)0.f;

    auto stage = [&](int dbase, int kc) {
        #pragma unroll
        for (int h = 0; h < 2; h++) {       // A: 8 subtiles over 4 waves x 2
            int sub = 4 * h + w;
            int r = sub * 16 + sr;
            int c = sp ^ SWZ(r);
            async_copy16(gA0 + (size_t)r * DIM + kc + c * 8, &lds[dbase + sub * 512]);
        }
        #pragma unroll
        for (int h = 0; h < 4; h++) {       // B: 16 subtiles
            int sub = 4 * h + w;
            int r = sub * 16 + sr;
            int c = sp ^ SWZ(r);
            async_copy16(gB0 + (size_t)r * DIM + kc + c * 8, &lds[dbase + 4096 + sub * 512]);
        }
    };

    // double-buffered K loop: issue next stage BEFORE compute; single barrier
    // per step (its implicit vmcnt(0) drains the prefetch after overlap).
    stage(0, 0);
    __syncthreads();
    for (int kt = 0; kt < DIM / BK; kt++) {
        const int base = (kt & 1) * 12288;
        if (kt < DIM / BK - 1) stage(12288 - base, (kt + 1) * BK);
        #pragma unroll
        for (int s = 0; s < 2; s++) {
            int c = 2 * s + lh;
            bf16x8 ah[2], bh[4];
            #pragma unroll
            for (int i = 0; i < 2; i++) {
                int r = wm * 64 + i * 32 + l31;
                ah[i] = *(const bf16x8*)&lds[base + r * 32 + ((c ^ SWZ(r)) * 8)];
            }
            #pragma unroll
            for (int j = 0; j < 4; j++) {
                int r = wn * 128 + j * 32 + l31;
                bh[j] = *(const bf16x8*)&lds[base + 4096 + r * 32 + ((c ^ SWZ(r)) * 8)];
            }
            #pragma unroll
            for (int i = 0; i < 2; i++)
                #pragma unroll
                for (int j = 0; j < 4; j++)
                    acc[i][j] = __builtin_amdgcn_mfma_f32_32x32x16_bf16(ah[i], bh[j], acc[i][j], 0, 0, 0);
        }
        __syncthreads();
    }

    // ---- epilogue: packed-key top-2; int2 dump, [64][66] scan ----
    const int colbase = wn * 128 + l31;
    int KA1 = 0, KA2 = 0, KB1 = 0, KB2 = 0;
    const int rl = t >> 2, q = t & 3;
    #pragma unroll
    for (int i = 0; i < 2; i++) {
        #pragma unroll
        for (int reg = 0; reg < 16; reg++) {
            int k0 = (__float_as_int(acc[i][0][reg] + 2.0f) & 0xFFFFFF00) | colbase;
            int k1 = (__float_as_int(acc[i][1][reg] + 2.0f) & 0xFFFFFF00) | (colbase + 32);
            int k2 = (__float_as_int(acc[i][2][reg] + 2.0f) & 0xFFFFFF00) | (colbase + 64);
            int k3 = (__float_as_int(acc[i][3][reg] + 2.0f) & 0xFFFFFF00) | (colbase + 96);
            int a = imax(k0, k1), b = imin(k0, k1);
            int c = imax(k2, k3), d = imin(k2, k3);
            int K1 = imax(a, c);
            int K2 = imax(imin(a, c), imax(b, d));
            int rr = wm * 32 + (reg & 3) + 8 * (reg >> 2) + 4 * lh;
            int slot = wn * 32 + l31;
            *(int2*)&kv[(rr * 66 + slot) * 2] = make_int2(K1, K2);
        }
        __syncthreads();
        // scan: thread (rl 0..63, q 0..3) covers slots q*16..+15 of local row rl
        int S1 = 0, S2 = 0;
        const int2* pr = (const int2*)&kv[(rl * 66 + q * 16) * 2];
        #pragma unroll
        for (int u = 0; u < 16; u++) {
            int2 e = pr[u];                  // e.x >= e.y (ordered pair)
            S2 = imax(imax(S2, e.y), imin(S1, e.x));
            S1 = imax(S1, e.x);
        }
        __syncthreads();
        #pragma unroll
        for (int d2 = 1; d2 <= 2; d2 <<= 1) {
            int o1 = __shfl_down(S1, d2), o2 = __shfl_down(S2, d2);
            S2 = imax(imax(S2, o2), imin(S1, o1));
            S1 = imax(S1, o1);
        }
        if (i == 0) { KA1 = S1; KA2 = S2; } else { KB1 = S1; KB2 = S2; }
    }
    if ((t & 3) == 0) {
        int rowA = (rl >> 5) * 64 + (rl & 31);   // i=0 rows
        int rowB = rowA + 32;                     // i=1 rows
        f32x4 ea;
        ea[0] = __int_as_float(KA1 & 0xFFFFFF00) - 2.0f;
        ea[1] = __int_as_float(nb + (KA1 & 0xFF));
        ea[2] = __int_as_float(KA2 & 0xFFFFFF00) - 2.0f;
        ea[3] = __int_as_float(nb + (KA2 & 0xFF));
        part[(size_t)blockIdx.y * NROWS + m0 + rowA] = ea;
        f32x4 eb;
        eb[0] = __int_as_float(KB1 & 0xFFFFFF00) - 2.0f;
        eb[1] = __int_as_float(nb + (KB1 & 0xFF));
        eb[2] = __int_as_float(KB2 & 0xFFFFFF00) - 2.0f;
        eb[3] = __int_as_float(nb + (KB2 & 0xFF));
        part[(size_t)blockIdx.y * NROWS + m0 + rowB] = eb;
    }
}

// ---------------- reduce + flag near-ties + collect block-top-2 candidates -------
__global__ void k_final(const f32x4* __restrict__ part, int* __restrict__ idx_ws,
                        float* __restrict__ out_idx, int* __restrict__ flags,
                        int* __restrict__ cnt, int* __restrict__ cand,
                        int* __restrict__ ccnt, float* __restrict__ v2q) {
    __shared__ f32x4 red[8][32];
    __shared__ float bcV1[32], bcV2[32];
    __shared__ int   lcc[32];
    __shared__ int   lcand[32][MAXC];
    __shared__ float sv2[8][32];
    const int nl = threadIdx.x & 31, sc = threadIdx.x >> 5;
    const int n = blockIdx.x * 32 + nl;
    if (threadIdx.x < 32) lcc[threadIdx.x] = 0;
    float V1 = -2e9f, V2 = -2e9f; int I1 = 0;
    for (int s = sc * 8; s < sc * 8 + 8; s++) {
        f32x4 e = part[(size_t)s * NROWS + n];
        float v1 = e[0]; int i1 = __float_as_int(e[1]); float v2 = e[2];
        V2 = fmaxf(fmaxf(V2, v2), fminf(v1, V1));
        I1 = (v1 > V1) ? i1 : I1;
        V1 = fmaxf(V1, v1);
    }
    f32x4 me; me[0] = V1; me[1] = __int_as_float(I1); me[2] = V2; me[3] = 0.f;
    red[sc][nl] = me;
    __syncthreads();
    if (threadIdx.x < 32) {
        float W1 = -2e9f, W2 = -2e9f; int J1 = 0;
        #pragma unroll
        for (int s2 = 0; s2 < 8; s2++) {
            f32x4 e = red[s2][threadIdx.x];
            float v1 = e[0]; int i1 = __float_as_int(e[1]); float v2 = e[2];
            W2 = fmaxf(fmaxf(W2, v2), fminf(v1, W1));
            J1 = (v1 > W1) ? i1 : J1;
            W1 = fmaxf(W1, v1);
        }
        int nn = blockIdx.x * 32 + threadIdx.x;
        idx_ws[nn] = J1;
        out_idx[nn] = (float)J1;
        bcV1[threadIdx.x] = W1;
        bcV2[threadIdx.x] = W2;
    }
    __syncthreads();
    float thr = bcV1[nl] - TAUC;
    float lv2 = -2e9f;
    for (int s = sc * 8; s < sc * 8 + 8; s++) {
        f32x4 e = part[(size_t)s * NROWS + n];
        if (e[0] >= thr) {
            int pos = atomicAdd(&lcc[nl], 2);
            if (pos < MAXC)     lcand[nl][pos]     = __float_as_int(e[1]);
            if (pos + 1 < MAXC) lcand[nl][pos + 1] = __float_as_int(e[3]);
            lv2 = fmaxf(lv2, e[2]);
        }
    }
    sv2[sc][nl] = lv2;
    __syncthreads();
    if (threadIdx.x < 32) {
        int nn = blockIdx.x * 32 + threadIdx.x;
        float W1 = bcV1[threadIdx.x], W2 = bcV2[threadIdx.x];
        if (W1 - W2 < GATE) {
            float m = -2e9f;
            #pragma unroll
            for (int s2 = 0; s2 < 8; s2++) m = fmaxf(m, sv2[s2][threadIdx.x]);
            int p = atomicAdd(cnt, 1);
            flags[p] = nn;
            ccnt[nn] = lcc[threadIdx.x];
            v2q[nn] = m;
            #pragma unroll
            for (int j = 0; j < MAXC; j++) cand[nn * MAXC + j] = lcand[threadIdx.x][j];
        }
    }
}

// ---------------- fp64 rescore of candidate columns (block per flagged row) ------
__launch_bounds__(256)
__global__ void k_rescan_cand(const int* __restrict__ flags, const int* __restrict__ cnt,
                              const int* __restrict__ cand, const int* __restrict__ ccnt,
                              const float* __restrict__ v2q,
                              const float* __restrict__ z, const float* __restrict__ emb,
                              const double* __restrict__ se2,
                              int* __restrict__ idx_ws, float* __restrict__ out_idx,
                              int* __restrict__ flags2, int* __restrict__ cnt2) {
    __shared__ double zs[DIM];
    __shared__ double wv[4];
    __shared__ int    wi[4];
    const int t = threadIdx.x, l = t & 63, w = t >> 6;
    const int F = *cnt;
    for (int f = blockIdx.x; f < F; f += gridDim.x) {
        int n = flags[f];
        int C = ccnt[n];
        int b = n >> 10, hw = n & 1023;
        __syncthreads();
        zs[t] = (double)z[(size_t)(b * DIM + t) * HW + hw];
        __syncthreads();
        double best = -2e18; int bi = 0x7fffffff;
        if (C <= MAXC) {
            double z0 = zs[l*4], z1 = zs[l*4+1], z2 = zs[l*4+2], z3 = zs[l*4+3];
            for (int cix = w; cix < C; cix += 4) {
                int k = cand[n * MAXC + cix];
                float4 ev = *(const float4*)(emb + (size_t)k * DIM + l * 4);
                double d = z0 * (double)ev.x + z1 * (double)ev.y
                         + z2 * (double)ev.z + z3 * (double)ev.w;
                #pragma unroll
                for (int o = 32; o > 0; o >>= 1) d += __shfl_down(d, o);
                if (l == 0) {
                    double qv = d / sqrt(se2[k]);
                    if (qv > best || (qv == best && k < bi)) { best = qv; bi = k; }
                }
            }
        }
        if (l == 0) { wv[w] = best; wi[w] = bi; }
        __syncthreads();
        if (t == 0) {
            if (C > MAXC) {
                int p = atomicAdd(cnt2, 1); flags2[p] = n;
            } else {
                double B = wv[0]; int BI = wi[0];
                #pragma unroll
                for (int x = 1; x < 4; x++)
                    if (wv[x] > B || (wv[x] == B && wi[x] < BI)) { B = wv[x]; BI = wi[x]; }
                if ((double)v2q[n] >= B - EHID) {
                    int p = atomicAdd(cnt2, 1); flags2[p] = n;   // possible hidden code
                } else {
                    idx_ws[n] = BI; out_idx[n] = (float)BI;
                }
            }
        }
    }
}

// ---------------- rare fallback: full fp64 scan (parallel over row x split) ------
__launch_bounds__(256)
__global__ void k_fullscan_part(const int* __restrict__ flags2, const int* __restrict__ cnt2,
                                const float* __restrict__ z, const float* __restrict__ emb,
                                const double* __restrict__ se2, double2* __restrict__ partial) {
    __shared__ double zs[DIM];
    __shared__ double wv[4];
    __shared__ int    wi[4];
    const int t = threadIdx.x, l = t & 63, w = t >> 6;
    const int W = (*cnt2) * 64;
    for (int item = blockIdx.x; item < W; item += gridDim.x) {
        int f = item >> 6, split = item & 63;
        int n = flags2[f];
        int b = n >> 10, hw = n & 1023;
        __syncthreads();
        zs[t] = (double)z[(size_t)(b * DIM + t) * HW + hw];
        __syncthreads();
        double z0 = zs[l*4], z1 = zs[l*4+1], z2 = zs[l*4+2], z3 = zs[l*4+3];
        double best = -2e18; int bi = 0;
        int kbase = split * 256 + w * 64;
        for (int p = 0; p < 64; p++) {
            int k = kbase + p;
            float4 ev = *(const float4*)(emb + (size_t)k * DIM + l * 4);
            double d = z0 * (double)ev.x + z1 * (double)ev.y
                     + z2 * (double)ev.z + z3 * (double)ev.w;
            #pragma unroll
            for (int o = 32; o > 0; o >>= 1) d += __shfl_down(d, o);
            if (l == 0) {
                double qv = d / sqrt(se2[k]);
                if (qv > best) { best = qv; bi = k; }
            }
        }
        if (l == 0) { wv[w] = best; wi[w] = bi; }
        __syncthreads();
        if (t == 0) {
            double B = wv[0]; int BI = wi[0];
            #pragma unroll
            for (int x = 1; x < 4; x++)
                if (wv[x] > B || (wv[x] == B && wi[x] < BI)) { B = wv[x]; BI = wi[x]; }
            partial[item] = make_double2(B, (double)BI);
        }
        __syncthreads();
    }
}

__global__ void k_fullscan_merge(const int* __restrict__ flags2, const int* __restrict__ cnt2,
                                 const double2* __restrict__ partial,
                                 int* __restrict__ idx_ws, float* __restrict__ out_idx) {
    const int F = *cnt2;
    const int l = threadIdx.x & 63, w = threadIdx.x >> 6;
    for (int f = blockIdx.x * 4 + w; f < F; f += gridDim.x * 4) {
        double2 e = partial[(size_t)f * 64 + l];
        double v = e.x; int i = (int)e.y;
        #pragma unroll
        for (int o = 32; o > 0; o >>= 1) {
            double ov = __shfl_down(v, o);
            int    oi = __shfl_down(i, o);
            if (ov > v || (ov == v && oi < i)) { v = ov; i = oi; }
        }
        if (l == 0) { int n = flags2[f]; idx_ws[n] = i; out_idx[n] = (float)i; }
    }
}

// ---------------- gather z_q = emb[idx] * inv_e[idx], grid (32, 8) ----------------
__global__ void k_zq(const int* __restrict__ idx_ws, const float* __restrict__ emb,
                     const float* __restrict__ inv_e, float* __restrict__ zq) {
    int t = threadIdx.x;
    int n = blockIdx.x * 256 + t;
    int b = n >> 10, hw = n & 1023;
    int c0 = blockIdx.y * 32;
    int id = idx_ws[n];
    float s = inv_e[id];
    const float* er = emb + (size_t)id * DIM;
    #pragma unroll
    for (int cc = 0; cc < 32; cc += 4) {
        float4 a = *(const float4*)(er + c0 + cc);
        zq[(size_t)(b * DIM + c0 + cc + 0) * HW + hw] = a.x * s;
        zq[(size_t)(b * DIM + c0 + cc + 1) * HW + hw] = a.y * s;
        zq[(size_t)(b * DIM + c0 + cc + 2) * HW + hw] = a.z * s;
        zq[(size_t)(b * DIM + c0 + cc + 3) * HW + hw] = a.w * s;
    }
}

extern "C" void kernel_launch(void* const* d_in, const int* in_sizes, int n_in,
                              void* d_out, int out_size, void* d_ws, size_t ws_size,
                              hipStream_t stream) {
    const float* z   = (const float*)d_in[0];
    const float* emb = (const float*)d_in[1];

    unsigned short* Zh = (unsigned short*)d_ws;           // 4 MB
    unsigned short* Eh = Zh + (size_t)NROWS * DIM;        // 8 MB
    float*  inv_e = (float*)(Eh + (size_t)NUM_E * DIM);   // 64 KB
    float*  zpart = inv_e + NUM_E;                        // 512 KB
    int*    idx_ws = (int*)(zpart + 16 * NROWS);          // 32 KB
    double* se2   = (double*)(idx_ws + NROWS);            // 128 KB
    int*    flags = (int*)(se2 + NUM_E);                  // 32 KB
    int*    flags2 = flags + NROWS;                       // 32 KB
    int*    cand  = flags2 + NROWS;                       // 512 KB (16/row)
    int*    ccnt  = cand + NROWS * MAXC;                  // 32 KB
    float*  v2q   = (float*)(ccnt + NROWS);               // 32 KB
    int*    cnt   = (int*)(v2q + NROWS);                  // 4 B
    int*    cnt2  = cnt + 1;                              // 4 B

    float* zq      = (float*)d_out;
    float* out_idx = zq + (size_t)NROWS * DIM;
    // part (8 MB) aliases the z_q region; consumed by k_final, then reused for
    // fullscan partials, finally overwritten with z_q by k_zq.
    f32x4*   part    = (f32x4*)zq;
    double2* partial = (double2*)zq;

    k_sumz   <<<dim3(NROWS / 256, 16), 256, 0, stream>>>(z, zpart);
    k_prep_z <<<dim3(NROWS / 64, DIM / 64), 256, 0, stream>>>(z, zpart, Zh);
    k_prep_e <<<NUM_E / 4, 256, 0, stream>>>(emb, inv_e, se2, Eh, cnt, cnt2);
    k_score  <<<dim3(NROWS / BM, NCB), 256, 0, stream>>>(Zh, Eh, part);
    k_final  <<<NROWS / 32, 256, 0, stream>>>(part, idx_ws, out_idx, flags, cnt,
                                              cand, ccnt, v2q);
    k_rescan_cand  <<<1024, 256, 0, stream>>>(flags, cnt, cand, ccnt, v2q, z, emb,
                                              se2, idx_ws, out_idx, flags2, cnt2);
    k_fullscan_part<<<2048, 256, 0, stream>>>(flags2, cnt2, z, emb, se2, partial);
    k_fullscan_merge<<<64, 256, 0, stream>>>(flags2, cnt2, partial, idx_ws, out_idx);
    k_zq     <<<dim3(NROWS / 256, 8), 256, 0, stream>>>(idx_ws, emb, inv_e, zq);
}

// Round 2
// 187.240 us; speedup vs baseline: 1.1651x; 1.0026x over previous
//
#include <hip/hip_runtime.h>

#define NUM_E   16384
#define DIM     256
#define NROWS   8192      // B*H*W
#define HW      1024      // H*W
#define BM      128
#define BN      256
#define BK      32
#define NCB     (NUM_E / BN)   // 64 col blocks
// thresholds: bf16 pairwise noise ~2.8e-4 (7 sigma = 2e-3) + 2x key-quantization 1.22e-4
#define GATE    2.5e-3f   // flag threshold
#define TAUC    2.5e-3f   // candidate-qualify threshold
#define EHID    2.5e-3    // hidden-code margin
#define MAXC    16

// 16-B chunk swizzle for staging (chunks 0..3 within a 32-short row)
#define SWZ(r) ((((r) >> 1) ^ ((r) >> 3)) & 3)

typedef __bf16 bf16x8 __attribute__((ext_vector_type(8)));
typedef float  f32x4  __attribute__((ext_vector_type(4)));
typedef float  f32x16 __attribute__((ext_vector_type(16)));

__device__ __forceinline__ unsigned short f2bf(float x) {
    unsigned u = __float_as_uint(x);
    unsigned r = (u + 0x7fffu + ((u >> 16) & 1u)) >> 16;
    return (unsigned short)r;
}
__device__ __forceinline__ void async_copy16(const void* g, void* l) {
    __builtin_amdgcn_global_load_lds(
        (const __attribute__((address_space(1))) unsigned int*)g,
        (__attribute__((address_space(3))) unsigned int*)l, 16, 0, 0);
}
__device__ __forceinline__ int imax(int a, int b) { return a > b ? a : b; }
__device__ __forceinline__ int imin(int a, int b) { return a < b ? a : b; }

// ---------------- z row sum-of-squares partials (grid 32 x 16) ----------------
__global__ void k_sumz(const float* __restrict__ z, float* __restrict__ zpart) {
    int n = blockIdx.x * 256 + threadIdx.x;
    int b = n >> 10, hw = n & 1023;
    int cb = blockIdx.y;
    const float* p = z + (size_t)(b * DIM + cb * 16) * HW + hw;
    float s = 0.f;
    #pragma unroll
    for (int c = 0; c < 16; c++) { float v = p[c * HW]; s += v * v; }
    zpart[cb * NROWS + n] = s;
}

// ---------------- prep z: finalize inv_z in-block + bf16 split (hi only) ---------
__global__ void k_prep_z(const float* __restrict__ z, const float* __restrict__ zpart,
                         unsigned short* __restrict__ Zh) {
    __shared__ float T[64 * 68];
    __shared__ __align__(16) float Tinv[64];
    int t = threadIdx.x;
    int n0 = blockIdx.x * 64, c0 = blockIdx.y * 64;
    int b = n0 >> 10, hw0 = n0 & 1023;
    if (t < 64) {
        float s = 0.f;
        #pragma unroll
        for (int cb = 0; cb < 16; cb++) s += zpart[cb * NROWS + n0 + t];
        Tinv[t] = 1.0f / fmaxf(sqrtf(s), 1e-12f);
    }
    __syncthreads();
    #pragma unroll
    for (int i = 0; i < 4; i++) {
        int f = t + 256 * i;
        int cc = f >> 4, n4 = (f & 15) * 4;
        float4 v  = *(const float4*)(z + (size_t)(b * DIM + c0 + cc) * HW + hw0 + n4);
        float4 iv = *(const float4*)&Tinv[n4];
        v.x *= iv.x; v.y *= iv.y; v.z *= iv.z; v.w *= iv.w;
        *(float4*)&T[cc * 68 + n4] = v;
    }
    __syncthreads();
    #pragma unroll
    for (int i = 0; i < 4; i++) {
        int f = t + 256 * i;
        int nn = f >> 4, c4 = (f & 15) * 4;
        ushort4 h;
        h.x = f2bf(T[(c4+0)*68 + nn]);
        h.y = f2bf(T[(c4+1)*68 + nn]);
        h.z = f2bf(T[(c4+2)*68 + nn]);
        h.w = f2bf(T[(c4+3)*68 + nn]);
        *(ushort4*)(Zh + (size_t)(n0 + nn) * DIM + c0 + c4) = h;
    }
}

// ---------------- prep e: fp64 norm + bf16 hi ----------------
__global__ void k_prep_e(const float* __restrict__ emb, float* __restrict__ inv_e,
                         double* __restrict__ se2, unsigned short* __restrict__ Eh,
                         int* __restrict__ cnt, int* __restrict__ cnt2) {
    if (blockIdx.x == 0 && threadIdx.x == 0) { *cnt = 0; *cnt2 = 0; }
    int wv = threadIdx.x >> 6, lane = threadIdx.x & 63;
    int k = blockIdx.x * 4 + wv;
    float4 v = *(const float4*)(emb + (size_t)k * DIM + lane * 4);
    double sq = (double)v.x*v.x + (double)v.y*v.y + (double)v.z*v.z + (double)v.w*v.w;
    for (int off = 32; off > 0; off >>= 1) sq += __shfl_down(sq, off);
    double tot = fmax(__shfl(sq, 0), 1e-24);
    if (lane == 0) { se2[k] = tot; inv_e[k] = 1.0f / fmaxf((float)sqrt(tot), 1e-12f); }
    float s = 1.0f / fmaxf((float)sqrt(tot), 1e-12f);
    ushort4 h;
    h.x = f2bf(v.x * s); h.y = f2bf(v.y * s); h.z = f2bf(v.z * s); h.w = f2bf(v.w * s);
    *(ushort4*)(Eh + (size_t)k * DIM + lane * 4) = h;
}

// ---------------- MFMA bf16 1-pass score: zh·eh, packed-key top-2 epilogue ----
// keys: v in [-1,1] -> bits(v+2.0f) is positive & order-preserving; low 8 bits
// replaced by block-local column (unique per col -> no exact ties; quantization
// step <= 2^-13, covered by GATE/TAUC/EHID margins + fp64 rescore path).
// K-loop: depth-2 prefetch, counted vmcnt(6) (never drains to 0 mid-loop),
// two raw barriers per step (m201-pattern fences).
__launch_bounds__(256, 2)
__global__ void k_score(const unsigned short* __restrict__ Zh,
                        const unsigned short* __restrict__ Eh, f32x4* __restrict__ part) {
    // union: staging 2 x (A 4096 | B 8192) shorts (48 KB)  /  epilogue kv[64][66] int2 (33 KB)
    __shared__ __align__(16) int smem[12288];
    unsigned short* lds = (unsigned short*)smem;
    int* kv = smem;
    const int t = threadIdx.x, l = t & 63, w = t >> 6;
    const int wm = w >> 1, wn = w & 1;      // wave tile 64 x 128
    const int m0 = blockIdx.x * BM;
    const int nb = blockIdx.y * BN;
    const int l31 = l & 31, lh = l >> 5;
    const int sr = l >> 2, sp = l & 3;

    const unsigned short* gA0 = Zh + (size_t)m0 * DIM;
    const unsigned short* gB0 = Eh + (size_t)nb * DIM;

    f32x16 acc[2][4];
    #pragma unroll
    for (int i = 0; i < 2; i++)
        #pragma unroll
        for (int j = 0; j < 4; j++) acc[i][j] = (f32x16)0.f;

    auto stage = [&](int dbase, int kc) {
        #pragma unroll
        for (int h = 0; h < 2; h++) {       // A: 8 subtiles over 4 waves x 2
            int sub = 4 * h + w;
            int r = sub * 16 + sr;
            int c = sp ^ SWZ(r);
            async_copy16(gA0 + (size_t)r * DIM + kc + c * 8, &lds[dbase + sub * 512]);
        }
        #pragma unroll
        for (int h = 0; h < 4; h++) {       // B: 16 subtiles
            int sub = 4 * h + w;
            int r = sub * 16 + sr;
            int c = sp ^ SWZ(r);
            async_copy16(gB0 + (size_t)r * DIM + kc + c * 8, &lds[dbase + 4096 + sub * 512]);
        }
    };

    // prologue: both buffers in flight (12 loads)
    stage(0, 0);
    stage(12288, BK);
    for (int kt = 0; kt < DIM / BK; kt++) {
        const int base = (kt & 1) * 12288;
        // wait only for the buffer we are about to read (oldest 6 of <=12)
        if (kt < DIM / BK - 1) asm volatile("s_waitcnt vmcnt(6)" ::: "memory");
        else                   asm volatile("s_waitcnt vmcnt(0)" ::: "memory");
        __builtin_amdgcn_s_barrier();
        asm volatile("" ::: "memory");
        __builtin_amdgcn_s_setprio(1);
        #pragma unroll
        for (int s = 0; s < 2; s++) {
            int c = 2 * s + lh;
            bf16x8 ah[2], bh[4];
            #pragma unroll
            for (int i = 0; i < 2; i++) {
                int r = wm * 64 + i * 32 + l31;
                ah[i] = *(const bf16x8*)&lds[base + r * 32 + ((c ^ SWZ(r)) * 8)];
            }
            #pragma unroll
            for (int j = 0; j < 4; j++) {
                int r = wn * 128 + j * 32 + l31;
                bh[j] = *(const bf16x8*)&lds[base + 4096 + r * 32 + ((c ^ SWZ(r)) * 8)];
            }
            #pragma unroll
            for (int i = 0; i < 2; i++)
                #pragma unroll
                for (int j = 0; j < 4; j++)
                    acc[i][j] = __builtin_amdgcn_mfma_f32_32x32x16_bf16(ah[i], bh[j], acc[i][j], 0, 0, 0);
        }
        __builtin_amdgcn_s_setprio(0);
        // all this wave's ds_reads serviced before anyone overwrites this buffer
        asm volatile("s_waitcnt lgkmcnt(0)" ::: "memory");
        __builtin_amdgcn_sched_barrier(0);
        __builtin_amdgcn_s_barrier();
        asm volatile("" ::: "memory");
        if (kt + 2 < DIM / BK) stage(base, (kt + 2) * BK);
    }

    // ---- epilogue: packed-key top-2; int2 dump, [64][66] scan ----
    const int colbase = wn * 128 + l31;
    int KA1 = 0, KA2 = 0, KB1 = 0, KB2 = 0;
    const int rl = t >> 2, q = t & 3;
    #pragma unroll
    for (int i = 0; i < 2; i++) {
        #pragma unroll
        for (int reg = 0; reg < 16; reg++) {
            int k0 = (__float_as_int(acc[i][0][reg] + 2.0f) & 0xFFFFFF00) | colbase;
            int k1 = (__float_as_int(acc[i][1][reg] + 2.0f) & 0xFFFFFF00) | (colbase + 32);
            int k2 = (__float_as_int(acc[i][2][reg] + 2.0f) & 0xFFFFFF00) | (colbase + 64);
            int k3 = (__float_as_int(acc[i][3][reg] + 2.0f) & 0xFFFFFF00) | (colbase + 96);
            int a = imax(k0, k1), b = imin(k0, k1);
            int c = imax(k2, k3), d = imin(k2, k3);
            int K1 = imax(a, c);
            int K2 = imax(imin(a, c), imax(b, d));
            int rr = wm * 32 + (reg & 3) + 8 * (reg >> 2) + 4 * lh;
            int slot = wn * 32 + l31;
            *(int2*)&kv[(rr * 66 + slot) * 2] = make_int2(K1, K2);
        }
        __syncthreads();
        // scan: thread (rl 0..63, q 0..3) covers slots q*16..+15 of local row rl;
        // start rotated by q so the 4 q-lanes hit different banks (q*16 int2 is
        // 128B-aligned -> q alone never enters the bank index).
        int S1 = 0, S2 = 0;
        const int2* pr = (const int2*)&kv[(rl * 66 + q * 16) * 2];
        #pragma unroll
        for (int u = 0; u < 16; u++) {
            int2 e = pr[(u + q) & 15];       // e.x >= e.y (ordered pair)
            S2 = imax(imax(S2, e.y), imin(S1, e.x));
            S1 = imax(S1, e.x);
        }
        __syncthreads();
        #pragma unroll
        for (int d2 = 1; d2 <= 2; d2 <<= 1) {
            int o1 = __shfl_down(S1, d2), o2 = __shfl_down(S2, d2);
            S2 = imax(imax(S2, o2), imin(S1, o1));
            S1 = imax(S1, o1);
        }
        if (i == 0) { KA1 = S1; KA2 = S2; } else { KB1 = S1; KB2 = S2; }
    }
    if ((t & 3) == 0) {
        int rowA = (rl >> 5) * 64 + (rl & 31);   // i=0 rows
        int rowB = rowA + 32;                     // i=1 rows
        f32x4 ea;
        ea[0] = __int_as_float(KA1 & 0xFFFFFF00) - 2.0f;
        ea[1] = __int_as_float(nb + (KA1 & 0xFF));
        ea[2] = __int_as_float(KA2 & 0xFFFFFF00) - 2.0f;
        ea[3] = __int_as_float(nb + (KA2 & 0xFF));
        part[(size_t)blockIdx.y * NROWS + m0 + rowA] = ea;
        f32x4 eb;
        eb[0] = __int_as_float(KB1 & 0xFFFFFF00) - 2.0f;
        eb[1] = __int_as_float(nb + (KB1 & 0xFF));
        eb[2] = __int_as_float(KB2 & 0xFFFFFF00) - 2.0f;
        eb[3] = __int_as_float(nb + (KB2 & 0xFF));
        part[(size_t)blockIdx.y * NROWS + m0 + rowB] = eb;
    }
}

// ---------------- reduce + flag near-ties + collect block-top-2 candidates -------
__global__ void k_final(const f32x4* __restrict__ part, int* __restrict__ idx_ws,
                        float* __restrict__ out_idx, int* __restrict__ flags,
                        int* __restrict__ cnt, int* __restrict__ cand,
                        int* __restrict__ ccnt, float* __restrict__ v2q) {
    __shared__ f32x4 red[8][32];
    __shared__ float bcV1[32], bcV2[32];
    __shared__ int   lcc[32];
    __shared__ int   lcand[32][MAXC];
    __shared__ float sv2[8][32];
    const int nl = threadIdx.x & 31, sc = threadIdx.x >> 5;
    const int n = blockIdx.x * 32 + nl;
    if (threadIdx.x < 32) lcc[threadIdx.x] = 0;
    float V1 = -2e9f, V2 = -2e9f; int I1 = 0;
    for (int s = sc * 8; s < sc * 8 + 8; s++) {
        f32x4 e = part[(size_t)s * NROWS + n];
        float v1 = e[0]; int i1 = __float_as_int(e[1]); float v2 = e[2];
        V2 = fmaxf(fmaxf(V2, v2), fminf(v1, V1));
        I1 = (v1 > V1) ? i1 : I1;
        V1 = fmaxf(V1, v1);
    }
    f32x4 me; me[0] = V1; me[1] = __int_as_float(I1); me[2] = V2; me[3] = 0.f;
    red[sc][nl] = me;
    __syncthreads();
    if (threadIdx.x < 32) {
        float W1 = -2e9f, W2 = -2e9f; int J1 = 0;
        #pragma unroll
        for (int s2 = 0; s2 < 8; s2++) {
            f32x4 e = red[s2][threadIdx.x];
            float v1 = e[0]; int i1 = __float_as_int(e[1]); float v2 = e[2];
            W2 = fmaxf(fmaxf(W2, v2), fminf(v1, W1));
            J1 = (v1 > W1) ? i1 : J1;
            W1 = fmaxf(W1, v1);
        }
        int nn = blockIdx.x * 32 + threadIdx.x;
        idx_ws[nn] = J1;
        out_idx[nn] = (float)J1;
        bcV1[threadIdx.x] = W1;
        bcV2[threadIdx.x] = W2;
    }
    __syncthreads();
    float thr = bcV1[nl] - TAUC;
    float lv2 = -2e9f;
    for (int s = sc * 8; s < sc * 8 + 8; s++) {
        f32x4 e = part[(size_t)s * NROWS + n];
        if (e[0] >= thr) {
            int pos = atomicAdd(&lcc[nl], 2);
            if (pos < MAXC)     lcand[nl][pos]     = __float_as_int(e[1]);
            if (pos + 1 < MAXC) lcand[nl][pos + 1] = __float_as_int(e[3]);
            lv2 = fmaxf(lv2, e[2]);
        }
    }
    sv2[sc][nl] = lv2;
    __syncthreads();
    if (threadIdx.x < 32) {
        int nn = blockIdx.x * 32 + threadIdx.x;
        float W1 = bcV1[threadIdx.x], W2 = bcV2[threadIdx.x];
        if (W1 - W2 < GATE) {
            float m = -2e9f;
            #pragma unroll
            for (int s2 = 0; s2 < 8; s2++) m = fmaxf(m, sv2[s2][threadIdx.x]);
            int p = atomicAdd(cnt, 1);
            flags[p] = nn;
            ccnt[nn] = lcc[threadIdx.x];
            v2q[nn] = m;
            #pragma unroll
            for (int j = 0; j < MAXC; j++) cand[nn * MAXC + j] = lcand[threadIdx.x][j];
        }
    }
}

// ---------------- fp64 rescore of candidate columns (block per flagged row) ------
__launch_bounds__(256)
__global__ void k_rescan_cand(const int* __restrict__ flags, const int* __restrict__ cnt,
                              const int* __restrict__ cand, const int* __restrict__ ccnt,
                              const float* __restrict__ v2q,
                              const float* __restrict__ z, const float* __restrict__ emb,
                              const double* __restrict__ se2,
                              int* __restrict__ idx_ws, float* __restrict__ out_idx,
                              int* __restrict__ flags2, int* __restrict__ cnt2) {
    __shared__ double zs[DIM];
    __shared__ double wv[4];
    __shared__ int    wi[4];
    const int t = threadIdx.x, l = t & 63, w = t >> 6;
    const int F = *cnt;
    for (int f = blockIdx.x; f < F; f += gridDim.x) {
        int n = flags[f];
        int C = ccnt[n];
        int b = n >> 10, hw = n & 1023;
        __syncthreads();
        zs[t] = (double)z[(size_t)(b * DIM + t) * HW + hw];
        __syncthreads();
        double best = -2e18; int bi = 0x7fffffff;
        if (C <= MAXC) {
            double z0 = zs[l*4], z1 = zs[l*4+1], z2 = zs[l*4+2], z3 = zs[l*4+3];
            for (int cix = w; cix < C; cix += 4) {
                int k = cand[n * MAXC + cix];
                float4 ev = *(const float4*)(emb + (size_t)k * DIM + l * 4);
                double d = z0 * (double)ev.x + z1 * (double)ev.y
                         + z2 * (double)ev.z + z3 * (double)ev.w;
                #pragma unroll
                for (int o = 32; o > 0; o >>= 1) d += __shfl_down(d, o);
                if (l == 0) {
                    double qv = d / sqrt(se2[k]);
                    if (qv > best || (qv == best && k < bi)) { best = qv; bi = k; }
                }
            }
        }
        if (l == 0) { wv[w] = best; wi[w] = bi; }
        __syncthreads();
        if (t == 0) {
            if (C > MAXC) {
                int p = atomicAdd(cnt2, 1); flags2[p] = n;
            } else {
                double B = wv[0]; int BI = wi[0];
                #pragma unroll
                for (int x = 1; x < 4; x++)
                    if (wv[x] > B || (wv[x] == B && wi[x] < BI)) { B = wv[x]; BI = wi[x]; }
                if ((double)v2q[n] >= B - EHID) {
                    int p = atomicAdd(cnt2, 1); flags2[p] = n;   // possible hidden code
                } else {
                    idx_ws[n] = BI; out_idx[n] = (float)BI;
                }
            }
        }
    }
}

// ---------------- rare fallback: full fp64 scan (parallel over row x split) ------
__launch_bounds__(256)
__global__ void k_fullscan_part(const int* __restrict__ flags2, const int* __restrict__ cnt2,
                                const float* __restrict__ z, const float* __restrict__ emb,
                                const double* __restrict__ se2, double2* __restrict__ partial) {
    __shared__ double zs[DIM];
    __shared__ double wv[4];
    __shared__ int    wi[4];
    const int t = threadIdx.x, l = t & 63, w = t >> 6;
    const int W = (*cnt2) * 64;
    for (int item = blockIdx.x; item < W; item += gridDim.x) {
        int f = item >> 6, split = item & 63;
        int n = flags2[f];
        int b = n >> 10, hw = n & 1023;
        __syncthreads();
        zs[t] = (double)z[(size_t)(b * DIM + t) * HW + hw];
        __syncthreads();
        double z0 = zs[l*4], z1 = zs[l*4+1], z2 = zs[l*4+2], z3 = zs[l*4+3];
        double best = -2e18; int bi = 0;
        int kbase = split * 256 + w * 64;
        for (int p = 0; p < 64; p++) {
            int k = kbase + p;
            float4 ev = *(const float4*)(emb + (size_t)k * DIM + l * 4);
            double d = z0 * (double)ev.x + z1 * (double)ev.y
                     + z2 * (double)ev.z + z3 * (double)ev.w;
            #pragma unroll
            for (int o = 32; o > 0; o >>= 1) d += __shfl_down(d, o);
            if (l == 0) {
                double qv = d / sqrt(se2[k]);
                if (qv > best) { best = qv; bi = k; }
            }
        }
        if (l == 0) { wv[w] = best; wi[w] = bi; }
        __syncthreads();
        if (t == 0) {
            double B = wv[0]; int BI = wi[0];
            #pragma unroll
            for (int x = 1; x < 4; x++)
                if (wv[x] > B || (wv[x] == B && wi[x] < BI)) { B = wv[x]; BI = wi[x]; }
            partial[item] = make_double2(B, (double)BI);
        }
        __syncthreads();
    }
}

__global__ void k_fullscan_merge(const int* __restrict__ flags2, const int* __restrict__ cnt2,
                                 const double2* __restrict__ partial,
                                 int* __restrict__ idx_ws, float* __restrict__ out_idx) {
    const int F = *cnt2;
    const int l = threadIdx.x & 63, w = threadIdx.x >> 6;
    for (int f = blockIdx.x * 4 + w; f < F; f += gridDim.x * 4) {
        double2 e = partial[(size_t)f * 64 + l];
        double v = e.x; int i = (int)e.y;
        #pragma unroll
        for (int o = 32; o > 0; o >>= 1) {
            double ov = __shfl_down(v, o);
            int    oi = __shfl_down(i, o);
            if (ov > v || (ov == v && oi < i)) { v = ov; i = oi; }
        }
        if (l == 0) { int n = flags2[f]; idx_ws[n] = i; out_idx[n] = (float)i; }
    }
}

// ---------------- gather z_q = emb[idx] * inv_e[idx], grid (32, 8) ----------------
__global__ void k_zq(const int* __restrict__ idx_ws, const float* __restrict__ emb,
                     const float* __restrict__ inv_e, float* __restrict__ zq) {
    int t = threadIdx.x;
    int n = blockIdx.x * 256 + t;
    int b = n >> 10, hw = n & 1023;
    int c0 = blockIdx.y * 32;
    int id = idx_ws[n];
    float s = inv_e[id];
    const float* er = emb + (size_t)id * DIM;
    #pragma unroll
    for (int cc = 0; cc < 32; cc += 4) {
        float4 a = *(const float4*)(er + c0 + cc);
        zq[(size_t)(b * DIM + c0 + cc + 0) * HW + hw] = a.x * s;
        zq[(size_t)(b * DIM + c0 + cc + 1) * HW + hw] = a.y * s;
        zq[(size_t)(b * DIM + c0 + cc + 2) * HW + hw] = a.z * s;
        zq[(size_t)(b * DIM + c0 + cc + 3) * HW + hw] = a.w * s;
    }
}

extern "C" void kernel_launch(void* const* d_in, const int* in_sizes, int n_in,
                              void* d_out, int out_size, void* d_ws, size_t ws_size,
                              hipStream_t stream) {
    const float* z   = (const float*)d_in[0];
    const float* emb = (const float*)d_in[1];

    unsigned short* Zh = (unsigned short*)d_ws;           // 4 MB
    unsigned short* Eh = Zh + (size_t)NROWS * DIM;        // 8 MB
    float*  inv_e = (float*)(Eh + (size_t)NUM_E * DIM);   // 64 KB
    float*  zpart = inv_e + NUM_E;                        // 512 KB
    int*    idx_ws = (int*)(zpart + 16 * NROWS);          // 32 KB
    double* se2   = (double*)(idx_ws + NROWS);            // 128 KB
    int*    flags = (int*)(se2 + NUM_E);                  // 32 KB
    int*    flags2 = flags + NROWS;                       // 32 KB
    int*    cand  = flags2 + NROWS;                       // 512 KB (16/row)
    int*    ccnt  = cand + NROWS * MAXC;                  // 32 KB
    float*  v2q   = (float*)(ccnt + NROWS);               // 32 KB
    int*    cnt   = (int*)(v2q + NROWS);                  // 4 B
    int*    cnt2  = cnt + 1;                              // 4 B

    float* zq      = (float*)d_out;
    float* out_idx = zq + (size_t)NROWS * DIM;
    // part (8 MB) aliases the z_q region; consumed by k_final, then reused for
    // fullscan partials, finally overwritten with z_q by k_zq.
    f32x4*   part    = (f32x4*)zq;
    double2* partial = (double2*)zq;

    k_sumz   <<<dim3(NROWS / 256, 16), 256, 0, stream>>>(z, zpart);
    k_prep_z <<<dim3(NROWS / 64, DIM / 64), 256, 0, stream>>>(z, zpart, Zh);
    k_prep_e <<<NUM_E / 4, 256, 0, stream>>>(emb, inv_e, se2, Eh, cnt, cnt2);
    k_score  <<<dim3(NROWS / BM, NCB), 256, 0, stream>>>(Zh, Eh, part);
    k_final  <<<NROWS / 32, 256, 0, stream>>>(part, idx_ws, out_idx, flags, cnt,
                                              cand, ccnt, v2q);
    k_rescan_cand  <<<1024, 256, 0, stream>>>(flags, cnt, cand, ccnt, v2q, z, emb,
                                              se2, idx_ws, out_idx, flags2, cnt2);
    k_fullscan_part<<<2048, 256, 0, stream>>>(flags2, cnt2, z, emb, se2, partial);
    k_fullscan_merge<<<64, 256, 0, stream>>>(flags2, cnt2, partial, idx_ws, out_idx);
    k_zq     <<<dim3(NROWS / 256, 8), 256, 0, stream>>>(idx_ws, emb, inv_e, zq);
}